// Round 1
// baseline (434.004 us; speedup 1.0000x reference)
//
#include <hip/hip_runtime.h>

// BSplineLayer: piecewise-linear spline eval.
// u: [4096,64,256] f32 (channel = fastest axis), knots/coefs: [256,64] f32.
// out[e] = c0 + (x-k0)/(k1-k0+eps) * (c1-c0), segment from searchsorted(left).
//
// Design:
//  - Each block owns a 64-channel group; knots+coefs staged in LDS with
//    stride 65 (bank = (c+j)%32 -> at most 2-way conflict = free).
//  - float4 load/store: thread t covers channels 4*(t%16)..+3; 16 lanes x 16B
//    = 256B contiguous segments -> coalesced.
//  - Segment lookup: analytic guess j = (x-kmin)*63/(kmax-kmin), then exact
//    compare fixup loops (general-correct for any sorted knots; ~0 iterations
//    for near-uniform knots, so negligible divergence).
//  - 1024 blocks = 4 groups x 256; 33.3KB LDS -> 4 blocks/CU resident
//    (16 waves/CU), one full residency wave, staging done once per block.

#define EPS 1e-6f
#define NCH_GROUP 64
#define STRIDE 65          // +1 pad: bank = (c + j) % 32 -> <=2-way conflict
#define NGROUPS 4
#define BLOCKS_PER_GROUP 256
#define ROWS_PER_TILE 16   // 256 threads / 16 col4-slots

__global__ __launch_bounds__(256) void bspline_kernel(
    const float* __restrict__ u, const float* __restrict__ knots,
    const float* __restrict__ coefs, float* __restrict__ out, int n_rows)
{
    __shared__ float sK[NCH_GROUP * STRIDE];
    __shared__ float sC[NCH_GROUP * STRIDE];

    const int t = threadIdx.x;
    const int g = blockIdx.x & (NGROUPS - 1);   // channel group 0..3
    const int b = blockIdx.x >> 2;              // block index within group

    // Stage this group's knots & coefs (4096 floats each, contiguous in HBM,
    // L2/L3-resident after first block) into padded LDS.
    const float* gk = knots + (size_t)g * NCH_GROUP * 64;
    const float* gc = coefs + (size_t)g * NCH_GROUP * 64;
    for (int i = t; i < NCH_GROUP * 64; i += 256) {
        int c = i >> 6;
        int k = i & 63;
        sK[c * STRIDE + k] = gk[i];
        sC[c * STRIDE + k] = gc[i];
    }
    __syncthreads();

    const int col4 = t & 15;        // which float4 column within the group
    const int rsub = t >> 4;        // row 0..15 within a tile
    const int lc = col4 * 4;        // local channel base (0..60)

    // Per-channel guess parameters (channels are fixed for this thread).
    float kmin[4], scale[4];
#pragma unroll
    for (int cc = 0; cc < 4; ++cc) {
        float klo = sK[(lc + cc) * STRIDE + 0];
        float khi = sK[(lc + cc) * STRIDE + 63];
        kmin[cc] = klo;
        scale[cc] = 63.0f * __builtin_amdgcn_rcpf(khi - klo);
    }

    const float4* u4 = (const float4*)u;
    float4* o4 = (float4*)out;
    const int colbase = g * 16 + col4;          // float4 column in [0,64)
    const int ntiles = n_rows / ROWS_PER_TILE;

    for (int rt = b; rt < ntiles; rt += BLOCKS_PER_GROUP) {
        int row = rt * ROWS_PER_TILE + rsub;
        size_t idx = (size_t)row * 64 + colbase;
        float4 x4 = u4[idx];
        float4 r;
        const float* xp = &x4.x;
        float* rp = &r.x;
#pragma unroll
        for (int cc = 0; cc < 4; ++cc) {
            float x = xp[cc];
            const float* kp = &sK[(lc + cc) * STRIDE];
            const float* cp = &sC[(lc + cc) * STRIDE];

            // Predictor: analytic segment guess (exact for uniform knots).
            float xs = (x - kmin[cc]) * scale[cc];
            int j = (int)xs;
            j = max(0, min(62, j));
            float k0 = kp[j];
            float k1 = kp[j + 1];
            // Corrector: exact-compare fixups. Final j satisfies
            // (j==0 || k[j] < x) && (j==62 || k[j+1] >= x)
            //   == clamp(searchsorted_left(k,x)-1, 0, 62) for any sorted k.
            while (j > 0 && k0 >= x) { --j; k1 = k0; k0 = kp[j]; }
            while (j < 62 && k1 < x) { ++j; k0 = k1; k1 = kp[j + 1]; }

            float tt = (x - k0) * __builtin_amdgcn_rcpf(k1 - k0 + EPS);
            float c0 = cp[j];
            float c1 = cp[j + 1];
            rp[cc] = fmaf(tt, c1 - c0, c0);
        }
        o4[idx] = r;
    }
}

extern "C" void kernel_launch(void* const* d_in, const int* in_sizes, int n_in,
                              void* d_out, int out_size, void* d_ws, size_t ws_size,
                              hipStream_t stream) {
    const float* u     = (const float*)d_in[0];
    const float* knots = (const float*)d_in[1];
    const float* coefs = (const float*)d_in[2];
    float* out = (float*)d_out;

    int n_rows = in_sizes[0] / 256;   // 262144 rows of 256 channels

    dim3 grid(NGROUPS * BLOCKS_PER_GROUP);   // 1024 blocks
    dim3 block(256);
    bspline_kernel<<<grid, block, 0, stream>>>(u, knots, coefs, out, n_rows);
}